// Round 13
// baseline (376.740 us; speedup 1.0000x reference)
//
#include <hip/hip_runtime.h>
#include <math.h>

// Problem constants
static const int kB = 32;
static const int kL = 1024;
static const int kH = 512;
static const int kN = 64;
static const int kNL = 4;
static const int kNFFT = 2048;

#define TWO_PI 6.283185307179586476925286766559

typedef float v2f __attribute__((ext_vector_type(2)));

// complex mul: (a.x b.x - a.y b.y, a.x b.y + a.y b.x)
__device__ __forceinline__ v2f cmul(v2f a, v2f b) {
    v2f axx = __builtin_shufflevector(a, a, 0, 0);
    v2f ayy = __builtin_shufflevector(a, a, 1, 1);
    v2f byx = __builtin_shufflevector(b, b, 1, 0);
    v2f t = ayy * byx;
    t.x = -t.x;
    return axx * b + t;     // v_pk_fma_f32
}

// j3 = fwd ? (t.y, -t.x) : (-t.y, t.x)
template<bool INV>
__device__ __forceinline__ v2f jrot(v2f t) {
    v2f r = __builtin_shufflevector(t, t, 1, 0);
    if (!INV) { r.y = -r.y; } else { r.x = -r.x; }
    return r;
}

// LDS swizzle: element i lives at i + (i>>4). All patterns land 4 lanes per
// bank-pair for b64 (bandwidth-optimal).
#define LDSZ 2176
__device__ __forceinline__ constexpr int swoff(int LGM, int u) {
    return (LGM == 0) ? u : (LGM == 3) ? (8 * u + (u >> 1)) : (68 * u);
}

// ---------------------------------------------------------------------------
// 8-point DFT in registers, natural order. INV=true -> conjugate transform.
// ---------------------------------------------------------------------------
template<bool INV>
__device__ __forceinline__ void dft8(const v2f c[8], v2f y[8]) {
    const float s = 0.70710678118654752440f;
    v2f t0 = c[0] + c[4], t1 = c[0] - c[4];
    v2f t2 = c[2] + c[6], t3 = c[2] - c[6];
    v2f e0 = t0 + t2, e2 = t0 - t2;
    v2f j3 = jrot<INV>(t3);
    v2f e1 = t1 + j3, e3 = t1 - j3;

    t0 = c[1] + c[5]; t1 = c[1] - c[5];
    t2 = c[3] + c[7]; t3 = c[3] - c[7];
    v2f o0 = t0 + t2, o2 = t0 - t2;
    v2f j3o = jrot<INV>(t3);
    v2f o1 = t1 + j3o, o3 = t1 - j3o;

    if (!INV) {
        v2f r1 = __builtin_shufflevector(o1, o1, 1, 0);
        o1 = s * (v2f){o1.x + r1.x, o1.y - r1.y};          // s(x+y, y-x)
        v2f r2 = __builtin_shufflevector(o2, o2, 1, 0);
        o2 = (v2f){r2.x, -r2.y};                            // (y, -x)
        v2f r3 = __builtin_shufflevector(o3, o3, 1, 0);
        o3 = s * (v2f){r3.x - o3.x, -r3.y - o3.y};          // s(y-x, -(x+y))
    } else {
        v2f r1 = __builtin_shufflevector(o1, o1, 1, 0);
        o1 = s * (v2f){o1.x - r1.x, o1.y + r1.y};          // s(x-y, x+y)
        v2f r2 = __builtin_shufflevector(o2, o2, 1, 0);
        o2 = (v2f){-r2.x, r2.y};                            // (-y, x)
        v2f r3 = __builtin_shufflevector(o3, o3, 1, 0);
        o3 = s * (v2f){-(o3.x + r3.x), r3.y - o3.y};        // (-s(x+y), s(x-y))
    }
    y[0] = e0 + o0; y[4] = e0 - o0;
    y[1] = e1 + o1; y[5] = e1 - o1;
    y[2] = e2 + o2; y[6] = e2 - o2;
    y[3] = e3 + o3; y[7] = e3 - o3;
}

// Forward dft8 with inputs c[4..7] == 0 (zero-padded half).
__device__ __forceinline__ void dft8h(const v2f c[4], v2f y[8]) {
    const float s = 0.70710678118654752440f;
    v2f e0 = c[0] + c[2], e2 = c[0] - c[2];
    v2f j  = jrot<false>(c[2]);
    v2f e1 = c[0] + j, e3 = c[0] - j;
    v2f o0 = c[1] + c[3], o2 = c[1] - c[3];
    v2f jo = jrot<false>(c[3]);
    v2f o1 = c[1] + jo, o3 = c[1] - jo;

    v2f r1 = __builtin_shufflevector(o1, o1, 1, 0);
    o1 = s * (v2f){o1.x + r1.x, o1.y - r1.y};
    v2f r2 = __builtin_shufflevector(o2, o2, 1, 0);
    o2 = (v2f){r2.x, -r2.y};
    v2f r3 = __builtin_shufflevector(o3, o3, 1, 0);
    o3 = s * (v2f){r3.x - o3.x, -r3.y - o3.y};

    y[0] = e0 + o0; y[4] = e0 - o0;
    y[1] = e1 + o1; y[5] = e1 - o1;
    y[2] = e2 + o2; y[6] = e2 - o2;
    y[3] = e3 + o3; y[7] = e3 - o3;
}

// Stockham radix-8 stage: dst[j*8m + i + u*m] = W_N^{jm*u} * y[u]
// Computed twiddles (R3/R7-proven).  Base angle in REVOLUTIONS into v_sin/cos.
template<bool INV, int LGM>
__device__ __forceinline__ void stage8_write(v2f* lds, int tid, v2f y[8]) {
    const int m = 1 << LGM;
    const int jm = tid & ~(m - 1);
    float rev = (INV ? (1.0f / 2048.0f) : (-1.0f / 2048.0f)) * (float)jm;
    v2f w1 = { __builtin_amdgcn_cosf(rev), __builtin_amdgcn_sinf(rev) };
    v2f w2 = cmul(w1, w1);
    v2f w3 = cmul(w2, w1);
    v2f w4 = cmul(w2, w2);
    v2f w5 = cmul(w3, w2);
    v2f w6 = cmul(w3, w3);
    v2f w7 = cmul(w4, w3);
    int base = ((tid >> LGM) << (LGM + 3)) + (tid & (m - 1));
    int swb = base + (base >> 4);
    lds[swb + swoff(LGM, 0)] = y[0];
    lds[swb + swoff(LGM, 1)] = cmul(w1, y[1]);
    lds[swb + swoff(LGM, 2)] = cmul(w2, y[2]);
    lds[swb + swoff(LGM, 3)] = cmul(w3, y[3]);
    lds[swb + swoff(LGM, 4)] = cmul(w4, y[4]);
    lds[swb + swoff(LGM, 5)] = cmul(w5, y[5]);
    lds[swb + swoff(LGM, 6)] = cmul(w6, y[6]);
    lds[swb + swoff(LGM, 7)] = cmul(w7, y[7]);
}

__device__ __forceinline__ void read8(const v2f* lds, int swb, v2f c[8]) {
#pragma unroll
    for (int s = 0; s < 8; ++s) c[s] = lds[swb + 272 * s];
}

// gelu (tanh approx) on a pair
__device__ __forceinline__ v2f gelu2(v2f v) {
    v2f v2 = v * v;
    v2f q = v2 * 0.044715f + 1.0f;
    v2f z = v * q * 1.5957691216057308f;
    v2f e;
    e.x = __expf(z.x); e.y = __expf(z.y);
    v2f den = e + 1.0f;
    v2f r;
    r.x = __builtin_amdgcn_rcpf(den.x);
    r.y = __builtin_amdgcn_rcpf(den.y);
    return v - v * r;
}

// ---------------------------------------------------------------------------
// SSM kernel K[h][l] + forward FFT -> Khat (pre-scaled by 1/2048).
// grid: (h=512, layers); layer = layer0 + blockIdx.y
// ---------------------------------------------------------------------------
__global__ __launch_bounds__(256) void kcomp_kernel(const float* __restrict__ log_dt,
                                                    const float* __restrict__ A_log,
                                                    const float* __restrict__ A_imag,
                                                    const float* __restrict__ C_re,
                                                    const float* __restrict__ C_im,
                                                    v2f* __restrict__ Khat,
                                                    int layer0, int out_stride)
{
    __shared__ v2f lds[LDSZ];
    __shared__ float dre_s[kN], g2re_s[kN], g2im_s[kN], hi_s[kN], lo_s[kN];
    __shared__ v2f w256_s[kN];

    int h = blockIdx.x, tid = threadIdx.x;
    int layer = layer0 + blockIdx.y;
    int swbase = tid + (tid >> 4);
    const size_t po = (size_t)layer * kH + h;

    if (tid < kN) {
        int n = tid;
        float dt  = expf(log_dt[po]);
        float Are = -expf(A_log[po * kN + n]);
        float Aim = A_imag[po * kN + n];
        float dre = dt * Are;
        float dim = dt * Aim;
        float er = expf(dre);
        float sw, cw;
        sincosf(dim, &sw, &cw);
        float emr = er * cw - 1.0f, emi = er * sw;
        float inv = 1.0f / (Are * Are + Aim * Aim);
        float air = Are * inv, aii = -Aim * inv;
        float br = emr * air - emi * aii;
        float bi = emr * aii + emi * air;
        float cr = C_re[po * kN + n], ci = C_im[po * kN + n];
        dre_s[n]  = dre;
        g2re_s[n] = 2.0f * (cr * br - ci * bi);
        g2im_s[n] = 2.0f * (cr * bi + ci * br);
        double dimrev = (double)dim * (1.0 / TWO_PI);
        float drf = (float)dimrev;
        float hi = __uint_as_float(__float_as_uint(drf) & 0xFFFFF000u);
        hi_s[n] = hi;
        lo_s[n] = (float)(dimrev - (double)hi);
        float mag256 = __expf(dre * 256.0f);
        double r2 = dimrev * 256.0;
        r2 -= floor(r2);
        float fr2 = (float)r2;
        w256_s[n] = (v2f){mag256 * __builtin_amdgcn_cosf(fr2),
                          mag256 * __builtin_amdgcn_sinf(fr2)};
    }
    __syncthreads();

    // K at l = tid + 256*s; rotation via packed cmul
    float acc0 = 0.f, acc1 = 0.f, acc2 = 0.f, acc3 = 0.f;
    const float lf = (float)tid;
    for (int n = 0; n < kN; ++n) {
        float dre  = dre_s[n];
        float g2re = g2re_s[n], g2im = g2im_s[n];
        float t1 = hi_s[n] * lf;            // exact
        float r1 = t1 - floorf(t1);
        float rv = r1 + lo_s[n] * lf;
        rv -= floorf(rv);                   // revolutions in [0,1)
        float mag = __expf(dre * lf);
        float sp = __builtin_amdgcn_sinf(rv);
        float cp = __builtin_amdgcn_cosf(rv);
        v2f pz = (v2f){mag * cp, mag * sp};
        v2f w = w256_s[n];
        acc0 += g2re * pz.x - g2im * pz.y;
        pz = cmul(pz, w);
        acc1 += g2re * pz.x - g2im * pz.y;
        pz = cmul(pz, w);
        acc2 += g2re * pz.x - g2im * pz.y;
        pz = cmul(pz, w);
        acc3 += g2re * pz.x - g2im * pz.y;
    }

    {   // forward stage 1 from registers (upper half zero)
        v2f c[4], y[8];
        c[0] = (v2f){acc0, 0.f}; c[1] = (v2f){acc1, 0.f};
        c[2] = (v2f){acc2, 0.f}; c[3] = (v2f){acc3, 0.f};
        dft8h(c, y);
        stage8_write<false, 0>(lds, tid, y);
    }
    __syncthreads();
    {
        v2f c[8], y[8];
        read8(lds, swbase, c);
        __syncthreads();
        dft8<false>(c, y);
        stage8_write<false, 3>(lds, tid, y);
    }
    __syncthreads();
    {
        v2f c[8], y[8];
        read8(lds, swbase, c);
        __syncthreads();
        dft8<false>(c, y);
        stage8_write<false, 6>(lds, tid, y);
    }
    __syncthreads();
    {   // radix-4 final stage (m=512, j=0) -> global, natural order, *1/2048
        const float invn = 1.0f / (float)kNFFT;
        v2f* outp = Khat + (size_t)(layer * out_stride + h) * kNFFT;
#pragma unroll
        for (int r = 0; r < 2; ++r) {
            v2f c0 = lds[swbase + 272 * r];
            v2f c1 = lds[swbase + 272 * r + 544];
            v2f c2 = lds[swbase + 272 * r + 1088];
            v2f c3 = lds[swbase + 272 * r + 1632];
            v2f t0 = c0 + c2, t1 = c0 - c2;
            v2f t2 = c1 + c3, t3 = c1 - c3;
            v2f j3 = jrot<false>(t3);
            int q = tid + (r << 8);
            outp[q]        = (t0 + t2) * invn;
            outp[q + 512]  = (t1 + j3) * invn;
            outp[q + 1024] = (t0 - t2) * invn;
            outp[q + 1536] = (t1 - j3) * invn;
        }
    }
}

// ---------------------------------------------------------------------------
// Layer-0 conv with FUSED embedding gather: us[s] comes straight from
// emb[x[b][l]][h] (8 scattered 4B loads + 8 coalesced x loads per thread)
// instead of a pre-materialized act.  Eliminates the embed pass and 128 MB
// of act write+read.  512 same-pair wgs read the same emb rows at
// consecutive h -> each 128B line serves 32 wgs (L2-friendly).
// Output (gelu) written to act for layer 1.  grid: (h=512, pair=16)
// ---------------------------------------------------------------------------
__global__ __launch_bounds__(256) void conv_first(const int* __restrict__ x,
                                                  const float* __restrict__ emb,
                                                  float* __restrict__ act,
                                                  const v2f* __restrict__ Khat,
                                                  const float* __restrict__ Dvec)
{
    __shared__ v2f lds[LDSZ];

    int h = blockIdx.x, pair = blockIdx.y, tid = threadIdx.x;
    int swbase = tid + (tid >> 4);
    const int* xa = x + (size_t)(2 * pair) * kL;
    const int* xb = xa + kL;
    float* rowa = act + ((size_t)(2 * pair) * kH + h) * kL;
    float* rowb = rowa + (size_t)kH * kL;

    v2f us[4];
#pragma unroll
    for (int s = 0; s < 4; ++s) {
        int l = tid + (s << 8);
        int xva = xa[l];
        int xvb = xb[l];
        us[s] = (v2f){emb[(size_t)xva * kH + h], emb[(size_t)xvb * kH + h]};
    }
    {
        v2f y[8];
        dft8h(us, y);
        stage8_write<false, 0>(lds, tid, y);
    }
    __syncthreads();
    {
        v2f c[8], y[8];
        read8(lds, swbase, c);
        __syncthreads();
        dft8<false>(c, y);
        stage8_write<false, 3>(lds, tid, y);
    }
    __syncthreads();
    {
        v2f c[8], y[8];
        read8(lds, swbase, c);
        __syncthreads();
        dft8<false>(c, y);
        stage8_write<false, 6>(lds, tid, y);
    }
    __syncthreads();
    {
        v2f cc[2][4];
#pragma unroll
        for (int r = 0; r < 2; ++r)
#pragma unroll
            for (int s = 0; s < 4; ++s)
                cc[r][s] = lds[swbase + 272 * r + 544 * s];
        __syncthreads();
        const v2f* kh = Khat + (size_t)h * kNFFT;
#pragma unroll
        for (int r = 0; r < 2; ++r) {
            v2f t0 = cc[r][0] + cc[r][2], t1 = cc[r][0] - cc[r][2];
            v2f t2 = cc[r][1] + cc[r][3], t3 = cc[r][1] - cc[r][3];
            v2f j3 = jrot<false>(t3);
            int q = tid + (r << 8);
            int swq = swbase + 272 * r;
            lds[swq]        = cmul(t0 + t2, kh[q]);
            lds[swq + 544]  = cmul(t1 + j3, kh[q + 512]);
            lds[swq + 1088] = cmul(t0 - t2, kh[q + 1024]);
            lds[swq + 1632] = cmul(t1 - j3, kh[q + 1536]);
        }
    }
    __syncthreads();
    {
        v2f c[8], y[8];
        read8(lds, swbase, c);
        __syncthreads();
        dft8<true>(c, y);
        stage8_write<true, 0>(lds, tid, y);
    }
    __syncthreads();
    {
        v2f c[8], y[8];
        read8(lds, swbase, c);
        __syncthreads();
        dft8<true>(c, y);
        stage8_write<true, 3>(lds, tid, y);
    }
    __syncthreads();
    {
        v2f c[8], y[8];
        read8(lds, swbase, c);
        __syncthreads();
        dft8<true>(c, y);
        stage8_write<true, 6>(lds, tid, y);
    }
    __syncthreads();
    {
        float Dh = Dvec[h];
#pragma unroll
        for (int r = 0; r < 2; ++r) {
            v2f c0 = lds[swbase + 272 * r];
            v2f c1 = lds[swbase + 272 * r + 544];
            v2f c2 = lds[swbase + 272 * r + 1088];
            v2f c3 = lds[swbase + 272 * r + 1632];
            v2f t0 = c0 + c2, t1 = c0 - c2;
            v2f t2 = c1 + c3, t3 = c1 - c3;
            v2f j3 = jrot<false>(t3);
            v2f y0 = t0 + t2;
            v2f y1 = t1 - j3;
            int l0 = tid + (r << 8);
            v2f g0 = gelu2(y0 + Dh * us[r]);
            v2f g1 = gelu2(y1 + Dh * us[r + 2]);
            rowa[l0]       = g0.x;
            rowb[l0]       = g0.y;
            rowa[l0 + 512] = g1.x;
            rowb[l0 + 512] = g1.y;
        }
    }
}

// ---------------------------------------------------------------------------
// Per-layer conv (R3/R8-proven codegen): rows (2*pair,h),(2*pair+1,h) packed
// as one complex signal; us[] in registers.  grid: (h=512, pair=16)
// ---------------------------------------------------------------------------
__global__ __launch_bounds__(256) void conv_kernel(float* __restrict__ act,
                                                   const v2f* __restrict__ Khat,
                                                   const float* __restrict__ Dvec)
{
    __shared__ v2f lds[LDSZ];

    int h = blockIdx.x, pair = blockIdx.y, tid = threadIdx.x;
    int swbase = tid + (tid >> 4);
    float* rowa = act + ((size_t)(2 * pair) * kH + h) * kL;
    float* rowb = rowa + (size_t)kH * kL;

    v2f us[4];
#pragma unroll
    for (int s = 0; s < 4; ++s) {
        int l = tid + (s << 8);
        us[s] = (v2f){rowa[l], rowb[l]};
    }
    {
        v2f y[8];
        dft8h(us, y);
        stage8_write<false, 0>(lds, tid, y);
    }
    __syncthreads();
    {
        v2f c[8], y[8];
        read8(lds, swbase, c);
        __syncthreads();
        dft8<false>(c, y);
        stage8_write<false, 3>(lds, tid, y);
    }
    __syncthreads();
    {
        v2f c[8], y[8];
        read8(lds, swbase, c);
        __syncthreads();
        dft8<false>(c, y);
        stage8_write<false, 6>(lds, tid, y);
    }
    __syncthreads();
    {
        v2f cc[2][4];
#pragma unroll
        for (int r = 0; r < 2; ++r)
#pragma unroll
            for (int s = 0; s < 4; ++s)
                cc[r][s] = lds[swbase + 272 * r + 544 * s];
        __syncthreads();
        const v2f* kh = Khat + (size_t)h * kNFFT;
#pragma unroll
        for (int r = 0; r < 2; ++r) {
            v2f t0 = cc[r][0] + cc[r][2], t1 = cc[r][0] - cc[r][2];
            v2f t2 = cc[r][1] + cc[r][3], t3 = cc[r][1] - cc[r][3];
            v2f j3 = jrot<false>(t3);
            int q = tid + (r << 8);
            int swq = swbase + 272 * r;
            lds[swq]        = cmul(t0 + t2, kh[q]);
            lds[swq + 544]  = cmul(t1 + j3, kh[q + 512]);
            lds[swq + 1088] = cmul(t0 - t2, kh[q + 1024]);
            lds[swq + 1632] = cmul(t1 - j3, kh[q + 1536]);
        }
    }
    __syncthreads();
    {
        v2f c[8], y[8];
        read8(lds, swbase, c);
        __syncthreads();
        dft8<true>(c, y);
        stage8_write<true, 0>(lds, tid, y);
    }
    __syncthreads();
    {
        v2f c[8], y[8];
        read8(lds, swbase, c);
        __syncthreads();
        dft8<true>(c, y);
        stage8_write<true, 3>(lds, tid, y);
    }
    __syncthreads();
    {
        v2f c[8], y[8];
        read8(lds, swbase, c);
        __syncthreads();
        dft8<true>(c, y);
        stage8_write<true, 6>(lds, tid, y);
    }
    __syncthreads();
    {
        float Dh = Dvec[h];
#pragma unroll
        for (int r = 0; r < 2; ++r) {
            v2f c0 = lds[swbase + 272 * r];
            v2f c1 = lds[swbase + 272 * r + 544];
            v2f c2 = lds[swbase + 272 * r + 1088];
            v2f c3 = lds[swbase + 272 * r + 1632];
            v2f t0 = c0 + c2, t1 = c0 - c2;
            v2f t2 = c1 + c3, t3 = c1 - c3;
            v2f j3 = jrot<false>(t3);
            v2f y0 = t0 + t2;
            v2f y1 = t1 - j3;
            int l0 = tid + (r << 8);
            v2f g0 = gelu2(y0 + Dh * us[r]);
            v2f g1 = gelu2(y1 + Dh * us[r + 2]);
            rowa[l0]       = g0.x;
            rowb[l0]       = g0.y;
            rowa[l0 + 512] = g1.x;
            rowb[l0 + 512] = g1.y;
        }
    }
}

// ---------------------------------------------------------------------------
// Last-layer conv + mean-pool partial (R8-proven epilogue: one plain store
// per wg, NO atomics, NO fences).  grid: (h=512, pair=16)
// ---------------------------------------------------------------------------
__global__ __launch_bounds__(256) void conv_final(const float* __restrict__ act,
                                                  const v2f* __restrict__ Khat,
                                                  const float* __restrict__ Dvec,
                                                  const float* __restrict__ fc_w,
                                                  v2f* __restrict__ partials)
{
    __shared__ v2f lds[LDSZ];
    __shared__ v2f wred[4];

    int h = blockIdx.x, pair = blockIdx.y, tid = threadIdx.x;
    int swbase = tid + (tid >> 4);
    const float* rowa = act + ((size_t)(2 * pair) * kH + h) * kL;
    const float* rowb = rowa + (size_t)kH * kL;

    v2f us[4];
#pragma unroll
    for (int s = 0; s < 4; ++s) {
        int l = tid + (s << 8);
        us[s] = (v2f){rowa[l], rowb[l]};
    }
    {
        v2f y[8];
        dft8h(us, y);
        stage8_write<false, 0>(lds, tid, y);
    }
    __syncthreads();
    {
        v2f c[8], y[8];
        read8(lds, swbase, c);
        __syncthreads();
        dft8<false>(c, y);
        stage8_write<false, 3>(lds, tid, y);
    }
    __syncthreads();
    {
        v2f c[8], y[8];
        read8(lds, swbase, c);
        __syncthreads();
        dft8<false>(c, y);
        stage8_write<false, 6>(lds, tid, y);
    }
    __syncthreads();
    {
        v2f cc[2][4];
#pragma unroll
        for (int r = 0; r < 2; ++r)
#pragma unroll
            for (int s = 0; s < 4; ++s)
                cc[r][s] = lds[swbase + 272 * r + 544 * s];
        __syncthreads();
        const v2f* kh = Khat + (size_t)h * kNFFT;
#pragma unroll
        for (int r = 0; r < 2; ++r) {
            v2f t0 = cc[r][0] + cc[r][2], t1 = cc[r][0] - cc[r][2];
            v2f t2 = cc[r][1] + cc[r][3], t3 = cc[r][1] - cc[r][3];
            v2f j3 = jrot<false>(t3);
            int q = tid + (r << 8);
            int swq = swbase + 272 * r;
            lds[swq]        = cmul(t0 + t2, kh[q]);
            lds[swq + 544]  = cmul(t1 + j3, kh[q + 512]);
            lds[swq + 1088] = cmul(t0 - t2, kh[q + 1024]);
            lds[swq + 1632] = cmul(t1 - j3, kh[q + 1536]);
        }
    }
    __syncthreads();
    {
        v2f c[8], y[8];
        read8(lds, swbase, c);
        __syncthreads();
        dft8<true>(c, y);
        stage8_write<true, 0>(lds, tid, y);
    }
    __syncthreads();
    {
        v2f c[8], y[8];
        read8(lds, swbase, c);
        __syncthreads();
        dft8<true>(c, y);
        stage8_write<true, 3>(lds, tid, y);
    }
    __syncthreads();
    {
        v2f c[8], y[8];
        read8(lds, swbase, c);
        __syncthreads();
        dft8<true>(c, y);
        stage8_write<true, 6>(lds, tid, y);
    }
    __syncthreads();
    v2f p = (v2f){0.f, 0.f};
    {
        float Dh = Dvec[h];
#pragma unroll
        for (int r = 0; r < 2; ++r) {
            v2f c0 = lds[swbase + 272 * r];
            v2f c1 = lds[swbase + 272 * r + 544];
            v2f c2 = lds[swbase + 272 * r + 1088];
            v2f c3 = lds[swbase + 272 * r + 1632];
            v2f t0 = c0 + c2, t1 = c0 - c2;
            v2f t2 = c1 + c3, t3 = c1 - c3;
            v2f j3 = jrot<false>(t3);
            v2f y0 = t0 + t2;
            v2f y1 = t1 - j3;
            p += gelu2(y0 + Dh * us[r]);
            p += gelu2(y1 + Dh * us[r + 2]);
        }
    }
#pragma unroll
    for (int off = 32; off > 0; off >>= 1) {
        p.x += __shfl_down(p.x, off);
        p.y += __shfl_down(p.y, off);
    }
    if ((tid & 63) == 0) wred[tid >> 6] = p;
    __syncthreads();
    if (tid == 0) {
        v2f t = wred[0] + wred[1] + wred[2] + wred[3];
        float scale = fc_w[h] * (1.0f / (float)kL);
        partials[(size_t)pair * kH + h] = t * scale;
    }
}

// ---------------------------------------------------------------------------
// Final reduction: out[2p], out[2p+1] = sum_h partials[p][h] + bias.
// grid: 16 (one per pair), 256 threads.
// ---------------------------------------------------------------------------
__global__ __launch_bounds__(256) void reduce_kernel(const v2f* __restrict__ partials,
                                                     const float* __restrict__ fc_b,
                                                     float* __restrict__ out)
{
    __shared__ v2f wred[4];
    int pair = blockIdx.x, tid = threadIdx.x;
    v2f p = partials[(size_t)pair * kH + tid] + partials[(size_t)pair * kH + tid + 256];
#pragma unroll
    for (int off = 32; off > 0; off >>= 1) {
        p.x += __shfl_down(p.x, off);
        p.y += __shfl_down(p.y, off);
    }
    if ((tid & 63) == 0) wred[tid >> 6] = p;
    __syncthreads();
    if (tid == 0) {
        v2f t = wred[0] + wred[1] + wred[2] + wred[3];
        float bias = fc_b[0];
        out[2 * pair]     = t.x + bias;
        out[2 * pair + 1] = t.y + bias;
    }
}

// ---------------------------------------------------------------------------
extern "C" void kernel_launch(void* const* d_in, const int* in_sizes, int n_in,
                              void* d_out, int out_size, void* d_ws, size_t ws_size,
                              hipStream_t stream)
{
    const int*   x         = (const int*)d_in[0];
    const float* embedding = (const float*)d_in[1];
    const float* log_dt    = (const float*)d_in[2];
    const float* A_log     = (const float*)d_in[3];
    const float* A_imag    = (const float*)d_in[4];
    const float* C_re      = (const float*)d_in[5];
    const float* C_im      = (const float*)d_in[6];
    const float* Dv        = (const float*)d_in[7];
    const float* fc_w      = (const float*)d_in[8];
    const float* fc_b      = (const float*)d_in[9];
    float* out = (float*)d_out;

    char* ws = (char*)d_ws;
    const size_t act_bytes  = (size_t)kB * kH * kL * sizeof(float);       // 64 MiB
    const size_t khat_bytes = (size_t)kH * kNFFT * sizeof(float) * 2;     // 8 MiB / layer
    float* act  = (float*)ws;
    v2f*   Khat = (v2f*)(ws + act_bytes);

    const bool multi = ws_size >= act_bytes + kNL * khat_bytes;           // 96 MiB

    if (multi) {
        // partials (64 KiB) alias Khat layer-0's region: dead once conv_first
        // completes; conv_final reads only layer 3's slot.
        v2f* partials = Khat;
        kcomp_kernel<<<dim3(kH, kNL), 256, 0, stream>>>(log_dt, A_log, A_imag,
                                                        C_re, C_im, Khat, 0, kH);
        conv_first<<<dim3(kH, kB / 2), 256, 0, stream>>>(
            x, embedding, act, Khat + (size_t)0 * kH * kNFFT, Dv);
        for (int layer = 1; layer < kNL - 1; ++layer) {
            conv_kernel<<<dim3(kH, kB / 2), 256, 0, stream>>>(
                act, Khat + (size_t)layer * kH * kNFFT, Dv + layer * kH);
        }
        conv_final<<<dim3(kH, kB / 2), 256, 0, stream>>>(
            act, Khat + (size_t)(kNL - 1) * kH * kNFFT,
            Dv + (kNL - 1) * kH, fc_w, partials);
        reduce_kernel<<<dim3(kB / 2), 256, 0, stream>>>(partials, fc_b, out);
    } else {
        // fallback: single Khat slot; partials in their own region after it
        v2f* partials = (v2f*)(ws + act_bytes + khat_bytes);
        kcomp_kernel<<<dim3(kH, 1), 256, 0, stream>>>(log_dt, A_log, A_imag,
                                                      C_re, C_im, Khat, 0, 0);
        conv_first<<<dim3(kH, kB / 2), 256, 0, stream>>>(x, embedding, act, Khat, Dv);
        for (int layer = 1; layer < kNL - 1; ++layer) {
            kcomp_kernel<<<dim3(kH, 1), 256, 0, stream>>>(log_dt, A_log, A_imag,
                                                          C_re, C_im, Khat, layer, 0);
            conv_kernel<<<dim3(kH, kB / 2), 256, 0, stream>>>(act, Khat, Dv + layer * kH);
        }
        kcomp_kernel<<<dim3(kH, 1), 256, 0, stream>>>(log_dt, A_log, A_imag,
                                                      C_re, C_im, Khat, kNL - 1, 0);
        conv_final<<<dim3(kH, kB / 2), 256, 0, stream>>>(act, Khat,
                                                         Dv + (kNL - 1) * kH, fc_w, partials);
        reduce_kernel<<<dim3(kB / 2), 256, 0, stream>>>(partials, fc_b, out);
    }
}

// Round 14
// 283.420 us; speedup vs baseline: 1.3293x; 1.3293x over previous
//
#include <hip/hip_runtime.h>
#include <math.h>

// Problem constants
static const int kB = 32;
static const int kL = 1024;
static const int kH = 512;
static const int kN = 64;
static const int kNL = 4;
static const int kNFFT = 2048;

#define TWO_PI 6.283185307179586476925286766559

typedef float v2f __attribute__((ext_vector_type(2)));
typedef float v4f __attribute__((ext_vector_type(4)));

// complex mul: (a.x b.x - a.y b.y, a.x b.y + a.y b.x)
__device__ __forceinline__ v2f cmul(v2f a, v2f b) {
    v2f axx = __builtin_shufflevector(a, a, 0, 0);
    v2f ayy = __builtin_shufflevector(a, a, 1, 1);
    v2f byx = __builtin_shufflevector(b, b, 1, 0);
    v2f t = ayy * byx;
    t.x = -t.x;
    return axx * b + t;     // v_pk_fma_f32
}

// j3 = fwd ? (t.y, -t.x) : (-t.y, t.x)
template<bool INV>
__device__ __forceinline__ v2f jrot(v2f t) {
    v2f r = __builtin_shufflevector(t, t, 1, 0);
    if (!INV) { r.y = -r.y; } else { r.x = -r.x; }
    return r;
}

// LDS swizzle: element i lives at i + (i>>4). All patterns land 4 lanes per
// bank-pair for b64 (bandwidth-optimal).
#define LDSZ 2176
__device__ __forceinline__ constexpr int swoff(int LGM, int u) {
    return (LGM == 0) ? u : (LGM == 3) ? (8 * u + (u >> 1)) : (68 * u);
}

// ---------------------------------------------------------------------------
// 8-point DFT in registers, natural order. INV=true -> conjugate transform.
// ---------------------------------------------------------------------------
template<bool INV>
__device__ __forceinline__ void dft8(const v2f c[8], v2f y[8]) {
    const float s = 0.70710678118654752440f;
    v2f t0 = c[0] + c[4], t1 = c[0] - c[4];
    v2f t2 = c[2] + c[6], t3 = c[2] - c[6];
    v2f e0 = t0 + t2, e2 = t0 - t2;
    v2f j3 = jrot<INV>(t3);
    v2f e1 = t1 + j3, e3 = t1 - j3;

    t0 = c[1] + c[5]; t1 = c[1] - c[5];
    t2 = c[3] + c[7]; t3 = c[3] - c[7];
    v2f o0 = t0 + t2, o2 = t0 - t2;
    v2f j3o = jrot<INV>(t3);
    v2f o1 = t1 + j3o, o3 = t1 - j3o;

    if (!INV) {
        v2f r1 = __builtin_shufflevector(o1, o1, 1, 0);
        o1 = s * (v2f){o1.x + r1.x, o1.y - r1.y};          // s(x+y, y-x)
        v2f r2 = __builtin_shufflevector(o2, o2, 1, 0);
        o2 = (v2f){r2.x, -r2.y};                            // (y, -x)
        v2f r3 = __builtin_shufflevector(o3, o3, 1, 0);
        o3 = s * (v2f){r3.x - o3.x, -r3.y - o3.y};          // s(y-x, -(x+y))
    } else {
        v2f r1 = __builtin_shufflevector(o1, o1, 1, 0);
        o1 = s * (v2f){o1.x - r1.x, o1.y + r1.y};          // s(x-y, x+y)
        v2f r2 = __builtin_shufflevector(o2, o2, 1, 0);
        o2 = (v2f){-r2.x, r2.y};                            // (-y, x)
        v2f r3 = __builtin_shufflevector(o3, o3, 1, 0);
        o3 = s * (v2f){-(o3.x + r3.x), r3.y - o3.y};        // (-s(x+y), s(x-y))
    }
    y[0] = e0 + o0; y[4] = e0 - o0;
    y[1] = e1 + o1; y[5] = e1 - o1;
    y[2] = e2 + o2; y[6] = e2 - o2;
    y[3] = e3 + o3; y[7] = e3 - o3;
}

// Forward dft8 with inputs c[4..7] == 0 (zero-padded half).
__device__ __forceinline__ void dft8h(const v2f c[4], v2f y[8]) {
    const float s = 0.70710678118654752440f;
    v2f e0 = c[0] + c[2], e2 = c[0] - c[2];
    v2f j  = jrot<false>(c[2]);
    v2f e1 = c[0] + j, e3 = c[0] - j;
    v2f o0 = c[1] + c[3], o2 = c[1] - c[3];
    v2f jo = jrot<false>(c[3]);
    v2f o1 = c[1] + jo, o3 = c[1] - jo;

    v2f r1 = __builtin_shufflevector(o1, o1, 1, 0);
    o1 = s * (v2f){o1.x + r1.x, o1.y - r1.y};
    v2f r2 = __builtin_shufflevector(o2, o2, 1, 0);
    o2 = (v2f){r2.x, -r2.y};
    v2f r3 = __builtin_shufflevector(o3, o3, 1, 0);
    o3 = s * (v2f){r3.x - o3.x, -r3.y - o3.y};

    y[0] = e0 + o0; y[4] = e0 - o0;
    y[1] = e1 + o1; y[5] = e1 - o1;
    y[2] = e2 + o2; y[6] = e2 - o2;
    y[3] = e3 + o3; y[7] = e3 - o3;
}

// Stockham radix-8 stage: dst[j*8m + i + u*m] = W_N^{jm*u} * y[u]
// Computed twiddles (R3/R7-proven).  Base angle in REVOLUTIONS into v_sin/cos.
template<bool INV, int LGM>
__device__ __forceinline__ void stage8_write(v2f* lds, int tid, v2f y[8]) {
    const int m = 1 << LGM;
    const int jm = tid & ~(m - 1);
    float rev = (INV ? (1.0f / 2048.0f) : (-1.0f / 2048.0f)) * (float)jm;
    v2f w1 = { __builtin_amdgcn_cosf(rev), __builtin_amdgcn_sinf(rev) };
    v2f w2 = cmul(w1, w1);
    v2f w3 = cmul(w2, w1);
    v2f w4 = cmul(w2, w2);
    v2f w5 = cmul(w3, w2);
    v2f w6 = cmul(w3, w3);
    v2f w7 = cmul(w4, w3);
    int base = ((tid >> LGM) << (LGM + 3)) + (tid & (m - 1));
    int swb = base + (base >> 4);
    lds[swb + swoff(LGM, 0)] = y[0];
    lds[swb + swoff(LGM, 1)] = cmul(w1, y[1]);
    lds[swb + swoff(LGM, 2)] = cmul(w2, y[2]);
    lds[swb + swoff(LGM, 3)] = cmul(w3, y[3]);
    lds[swb + swoff(LGM, 4)] = cmul(w4, y[4]);
    lds[swb + swoff(LGM, 5)] = cmul(w5, y[5]);
    lds[swb + swoff(LGM, 6)] = cmul(w6, y[6]);
    lds[swb + swoff(LGM, 7)] = cmul(w7, y[7]);
}

__device__ __forceinline__ void read8(const v2f* lds, int swb, v2f c[8]) {
#pragma unroll
    for (int s = 0; s < 8; ++s) c[s] = lds[swb + 272 * s];
}

// gelu (tanh approx) on a pair
__device__ __forceinline__ v2f gelu2(v2f v) {
    v2f v2 = v * v;
    v2f q = v2 * 0.044715f + 1.0f;
    v2f z = v * q * 1.5957691216057308f;
    v2f e;
    e.x = __expf(z.x); e.y = __expf(z.y);
    v2f den = e + 1.0f;
    v2f r;
    r.x = __builtin_amdgcn_rcpf(den.x);
    r.y = __builtin_amdgcn_rcpf(den.y);
    return v - v * r;
}

// ---------------------------------------------------------------------------
// Shared device bodies for embed / kcomp (fused + standalone kernels).
// embed: float4 gather from emb (full-line utilization per row — the R13
// column-gather alternative fetched 492 MB from HBM and was 2.5x slower).
// ---------------------------------------------------------------------------
__device__ __forceinline__ void embed_body(const int* __restrict__ x,
                                           const float* __restrict__ emb,
                                           float* __restrict__ act,
                                           char* smem, int hb, int lb, int b, int tid)
{
    float (*tile)[65] = (float (*)[65])smem;
    int h0 = hb * 64, l0 = lb * 64;
    const v4f* emb4 = (const v4f*)emb;
#pragma unroll
    for (int k = 0; k < 4; ++k) {
        int idx = (k << 8) + tid;
        int li = idx >> 4, hv = idx & 15;
        int xv = x[b * kL + l0 + li];
        v4f v = emb4[(size_t)xv * (kH >> 2) + (h0 >> 2) + hv];
        int c0 = hv << 2;
        tile[li][c0]     = v.x;
        tile[li][c0 + 1] = v.y;
        tile[li][c0 + 2] = v.z;
        tile[li][c0 + 3] = v.w;
    }
    __syncthreads();
#pragma unroll
    for (int k = 0; k < 16; ++k) {
        int idx = (k << 8) + tid;
        int hi = idx >> 6, li = idx & 63;
        act[((size_t)b * kH + h0 + hi) * kL + l0 + li] = tile[li][hi];
    }
}

__device__ __forceinline__ void kcomp_body(const float* __restrict__ log_dt,
                                           const float* __restrict__ A_log,
                                           const float* __restrict__ A_imag,
                                           const float* __restrict__ C_re,
                                           const float* __restrict__ C_im,
                                           v2f* __restrict__ Khat,
                                           char* smem, int h, int layer,
                                           int out_stride, int tid)
{
    v2f*   lds    = (v2f*)smem;                    // 17408 B
    float* dre_s  = (float*)(smem + 17408);
    float* g2re_s = (float*)(smem + 17664);
    float* g2im_s = (float*)(smem + 17920);
    float* hi_s   = (float*)(smem + 18176);
    float* lo_s   = (float*)(smem + 18432);
    v2f*   w256_s = (v2f*)(smem + 18688);          // -> end 19200

    int swbase = tid + (tid >> 4);
    const size_t po = (size_t)layer * kH + h;

    if (tid < kN) {
        int n = tid;
        float dt  = expf(log_dt[po]);
        float Are = -expf(A_log[po * kN + n]);
        float Aim = A_imag[po * kN + n];
        float dre = dt * Are;
        float dim = dt * Aim;
        float er = expf(dre);
        float sw, cw;
        sincosf(dim, &sw, &cw);
        float emr = er * cw - 1.0f, emi = er * sw;
        float inv = 1.0f / (Are * Are + Aim * Aim);
        float air = Are * inv, aii = -Aim * inv;
        float br = emr * air - emi * aii;
        float bi = emr * aii + emi * air;
        float cr = C_re[po * kN + n], ci = C_im[po * kN + n];
        dre_s[n]  = dre;
        g2re_s[n] = 2.0f * (cr * br - ci * bi);
        g2im_s[n] = 2.0f * (cr * bi + ci * br);
        double dimrev = (double)dim * (1.0 / TWO_PI);
        float drf = (float)dimrev;
        float hi = __uint_as_float(__float_as_uint(drf) & 0xFFFFF000u);
        hi_s[n] = hi;
        lo_s[n] = (float)(dimrev - (double)hi);
        float mag256 = __expf(dre * 256.0f);
        double r2 = dimrev * 256.0;
        r2 -= floor(r2);
        float fr2 = (float)r2;
        w256_s[n] = (v2f){mag256 * __builtin_amdgcn_cosf(fr2),
                          mag256 * __builtin_amdgcn_sinf(fr2)};
    }
    __syncthreads();

    // K at l = tid + 256*s; rotation packed as v2f cmul
    float acc0 = 0.f, acc1 = 0.f, acc2 = 0.f, acc3 = 0.f;
    const float lf = (float)tid;
    for (int n = 0; n < kN; ++n) {
        float dre  = dre_s[n];
        float g2re = g2re_s[n], g2im = g2im_s[n];
        float t1 = hi_s[n] * lf;            // exact
        float r1 = t1 - floorf(t1);
        float rv = r1 + lo_s[n] * lf;
        rv -= floorf(rv);                   // revolutions in [0,1)
        float mag = __expf(dre * lf);
        float sp = __builtin_amdgcn_sinf(rv);
        float cp = __builtin_amdgcn_cosf(rv);
        v2f pz = (v2f){mag * cp, mag * sp};
        v2f w = w256_s[n];
        acc0 += g2re * pz.x - g2im * pz.y;
        pz = cmul(pz, w);
        acc1 += g2re * pz.x - g2im * pz.y;
        pz = cmul(pz, w);
        acc2 += g2re * pz.x - g2im * pz.y;
        pz = cmul(pz, w);
        acc3 += g2re * pz.x - g2im * pz.y;
    }

    {   // forward stage 1 from registers (upper half zero)
        v2f c[4], y[8];
        c[0] = (v2f){acc0, 0.f}; c[1] = (v2f){acc1, 0.f};
        c[2] = (v2f){acc2, 0.f}; c[3] = (v2f){acc3, 0.f};
        dft8h(c, y);
        stage8_write<false, 0>(lds, tid, y);
    }
    __syncthreads();
    {
        v2f c[8], y[8];
        read8(lds, swbase, c);
        __syncthreads();
        dft8<false>(c, y);
        stage8_write<false, 3>(lds, tid, y);
    }
    __syncthreads();
    {
        v2f c[8], y[8];
        read8(lds, swbase, c);
        __syncthreads();
        dft8<false>(c, y);
        stage8_write<false, 6>(lds, tid, y);
    }
    __syncthreads();
    {   // radix-4 final stage (m=512, j=0) -> global, natural order, *1/2048
        const float invn = 1.0f / (float)kNFFT;
        v2f* outp = Khat + (size_t)(layer * out_stride + h) * kNFFT;
#pragma unroll
        for (int r = 0; r < 2; ++r) {
            v2f c0 = lds[swbase + 272 * r];
            v2f c1 = lds[swbase + 272 * r + 544];
            v2f c2 = lds[swbase + 272 * r + 1088];
            v2f c3 = lds[swbase + 272 * r + 1632];
            v2f t0 = c0 + c2, t1 = c0 - c2;
            v2f t2 = c1 + c3, t3 = c1 - c3;
            v2f j3 = jrot<false>(t3);
            int q = tid + (r << 8);
            outp[q]        = (t0 + t2) * invn;
            outp[q + 512]  = (t1 + j3) * invn;
            outp[q + 1024] = (t0 - t2) * invn;
            outp[q + 1536] = (t1 - j3) * invn;
        }
    }
}

// ---------------------------------------------------------------------------
// Fused prep: wgs [0,2048) run kcomp (4 layers x 512 h), wgs [2048,6144) run
// embed.  kcomp first so long wgs fill CUs; embed streams in behind.
// ---------------------------------------------------------------------------
__global__ __launch_bounds__(256) void prep_kernel(const int* __restrict__ x,
                                                   const float* __restrict__ emb,
                                                   float* __restrict__ act,
                                                   const float* __restrict__ log_dt,
                                                   const float* __restrict__ A_log,
                                                   const float* __restrict__ A_imag,
                                                   const float* __restrict__ C_re,
                                                   const float* __restrict__ C_im,
                                                   v2f* __restrict__ Khat)
{
    __shared__ __align__(16) char smem[19200];
    int w = blockIdx.x, tid = threadIdx.x;
    if (w < 2048) {
        kcomp_body(log_dt, A_log, A_imag, C_re, C_im, Khat,
                   smem, w & 511, w >> 9, kH, tid);
    } else {
        int id = w - 2048;
        embed_body(x, emb, act, smem, id & 7, (id >> 3) & 15, id >> 7, tid);
    }
}

// Standalone kernels (fallback path)
__global__ __launch_bounds__(256) void embed_kernel(const int* __restrict__ x,
                                                    const float* __restrict__ emb,
                                                    float* __restrict__ act)
{
    __shared__ __align__(16) char smem[19200];
    int id = blockIdx.x;
    embed_body(x, emb, act, smem, id & 7, (id >> 3) & 15, id >> 7, threadIdx.x);
}

__global__ __launch_bounds__(256) void kcomp_kernel(const float* __restrict__ log_dt,
                                                    const float* __restrict__ A_log,
                                                    const float* __restrict__ A_imag,
                                                    const float* __restrict__ C_re,
                                                    const float* __restrict__ C_im,
                                                    v2f* __restrict__ Khat,
                                                    int layer0, int out_stride)
{
    __shared__ __align__(16) char smem[19200];
    kcomp_body(log_dt, A_log, A_imag, C_re, C_im, Khat,
               smem, blockIdx.x, layer0 + blockIdx.y, out_stride, threadIdx.x);
}

// ---------------------------------------------------------------------------
// Per-layer conv (R3/R8-proven codegen): rows (2*pair,h),(2*pair+1,h) packed
// as one complex signal; us[] in registers.  grid: (h=512, pair=16)
// ---------------------------------------------------------------------------
__global__ __launch_bounds__(256) void conv_kernel(float* __restrict__ act,
                                                   const v2f* __restrict__ Khat,
                                                   const float* __restrict__ Dvec)
{
    __shared__ v2f lds[LDSZ];

    int h = blockIdx.x, pair = blockIdx.y, tid = threadIdx.x;
    int swbase = tid + (tid >> 4);
    float* rowa = act + ((size_t)(2 * pair) * kH + h) * kL;
    float* rowb = rowa + (size_t)kH * kL;

    v2f us[4];
#pragma unroll
    for (int s = 0; s < 4; ++s) {
        int l = tid + (s << 8);
        us[s] = (v2f){rowa[l], rowb[l]};
    }
    {
        v2f y[8];
        dft8h(us, y);
        stage8_write<false, 0>(lds, tid, y);
    }
    __syncthreads();
    {
        v2f c[8], y[8];
        read8(lds, swbase, c);
        __syncthreads();
        dft8<false>(c, y);
        stage8_write<false, 3>(lds, tid, y);
    }
    __syncthreads();
    {
        v2f c[8], y[8];
        read8(lds, swbase, c);
        __syncthreads();
        dft8<false>(c, y);
        stage8_write<false, 6>(lds, tid, y);
    }
    __syncthreads();
    {
        v2f cc[2][4];
#pragma unroll
        for (int r = 0; r < 2; ++r)
#pragma unroll
            for (int s = 0; s < 4; ++s)
                cc[r][s] = lds[swbase + 272 * r + 544 * s];
        __syncthreads();
        const v2f* kh = Khat + (size_t)h * kNFFT;
#pragma unroll
        for (int r = 0; r < 2; ++r) {
            v2f t0 = cc[r][0] + cc[r][2], t1 = cc[r][0] - cc[r][2];
            v2f t2 = cc[r][1] + cc[r][3], t3 = cc[r][1] - cc[r][3];
            v2f j3 = jrot<false>(t3);
            int q = tid + (r << 8);
            int swq = swbase + 272 * r;
            lds[swq]        = cmul(t0 + t2, kh[q]);
            lds[swq + 544]  = cmul(t1 + j3, kh[q + 512]);
            lds[swq + 1088] = cmul(t0 - t2, kh[q + 1024]);
            lds[swq + 1632] = cmul(t1 - j3, kh[q + 1536]);
        }
    }
    __syncthreads();
    {
        v2f c[8], y[8];
        read8(lds, swbase, c);
        __syncthreads();
        dft8<true>(c, y);
        stage8_write<true, 0>(lds, tid, y);
    }
    __syncthreads();
    {
        v2f c[8], y[8];
        read8(lds, swbase, c);
        __syncthreads();
        dft8<true>(c, y);
        stage8_write<true, 3>(lds, tid, y);
    }
    __syncthreads();
    {
        v2f c[8], y[8];
        read8(lds, swbase, c);
        __syncthreads();
        dft8<true>(c, y);
        stage8_write<true, 6>(lds, tid, y);
    }
    __syncthreads();
    {
        float Dh = Dvec[h];
#pragma unroll
        for (int r = 0; r < 2; ++r) {
            v2f c0 = lds[swbase + 272 * r];
            v2f c1 = lds[swbase + 272 * r + 544];
            v2f c2 = lds[swbase + 272 * r + 1088];
            v2f c3 = lds[swbase + 272 * r + 1632];
            v2f t0 = c0 + c2, t1 = c0 - c2;
            v2f t2 = c1 + c3, t3 = c1 - c3;
            v2f j3 = jrot<false>(t3);
            v2f y0 = t0 + t2;
            v2f y1 = t1 - j3;
            int l0 = tid + (r << 8);
            v2f g0 = gelu2(y0 + Dh * us[r]);
            v2f g1 = gelu2(y1 + Dh * us[r + 2]);
            rowa[l0]       = g0.x;
            rowb[l0]       = g0.y;
            rowa[l0 + 512] = g1.x;
            rowb[l0 + 512] = g1.y;
        }
    }
}

// ---------------------------------------------------------------------------
// Last-layer conv + mean-pool partial (R8-proven epilogue: one plain store
// per wg, NO atomics, NO fences).  grid: (h=512, pair=16)
// ---------------------------------------------------------------------------
__global__ __launch_bounds__(256) void conv_final(const float* __restrict__ act,
                                                  const v2f* __restrict__ Khat,
                                                  const float* __restrict__ Dvec,
                                                  const float* __restrict__ fc_w,
                                                  v2f* __restrict__ partials)
{
    __shared__ v2f lds[LDSZ];
    __shared__ v2f wred[4];

    int h = blockIdx.x, pair = blockIdx.y, tid = threadIdx.x;
    int swbase = tid + (tid >> 4);
    const float* rowa = act + ((size_t)(2 * pair) * kH + h) * kL;
    const float* rowb = rowa + (size_t)kH * kL;

    v2f us[4];
#pragma unroll
    for (int s = 0; s < 4; ++s) {
        int l = tid + (s << 8);
        us[s] = (v2f){rowa[l], rowb[l]};
    }
    {
        v2f y[8];
        dft8h(us, y);
        stage8_write<false, 0>(lds, tid, y);
    }
    __syncthreads();
    {
        v2f c[8], y[8];
        read8(lds, swbase, c);
        __syncthreads();
        dft8<false>(c, y);
        stage8_write<false, 3>(lds, tid, y);
    }
    __syncthreads();
    {
        v2f c[8], y[8];
        read8(lds, swbase, c);
        __syncthreads();
        dft8<false>(c, y);
        stage8_write<false, 6>(lds, tid, y);
    }
    __syncthreads();
    {
        v2f cc[2][4];
#pragma unroll
        for (int r = 0; r < 2; ++r)
#pragma unroll
            for (int s = 0; s < 4; ++s)
                cc[r][s] = lds[swbase + 272 * r + 544 * s];
        __syncthreads();
        const v2f* kh = Khat + (size_t)h * kNFFT;
#pragma unroll
        for (int r = 0; r < 2; ++r) {
            v2f t0 = cc[r][0] + cc[r][2], t1 = cc[r][0] - cc[r][2];
            v2f t2 = cc[r][1] + cc[r][3], t3 = cc[r][1] - cc[r][3];
            v2f j3 = jrot<false>(t3);
            int q = tid + (r << 8);
            int swq = swbase + 272 * r;
            lds[swq]        = cmul(t0 + t2, kh[q]);
            lds[swq + 544]  = cmul(t1 + j3, kh[q + 512]);
            lds[swq + 1088] = cmul(t0 - t2, kh[q + 1024]);
            lds[swq + 1632] = cmul(t1 - j3, kh[q + 1536]);
        }
    }
    __syncthreads();
    {
        v2f c[8], y[8];
        read8(lds, swbase, c);
        __syncthreads();
        dft8<true>(c, y);
        stage8_write<true, 0>(lds, tid, y);
    }
    __syncthreads();
    {
        v2f c[8], y[8];
        read8(lds, swbase, c);
        __syncthreads();
        dft8<true>(c, y);
        stage8_write<true, 3>(lds, tid, y);
    }
    __syncthreads();
    {
        v2f c[8], y[8];
        read8(lds, swbase, c);
        __syncthreads();
        dft8<true>(c, y);
        stage8_write<true, 6>(lds, tid, y);
    }
    __syncthreads();
    v2f p = (v2f){0.f, 0.f};
    {
        float Dh = Dvec[h];
#pragma unroll
        for (int r = 0; r < 2; ++r) {
            v2f c0 = lds[swbase + 272 * r];
            v2f c1 = lds[swbase + 272 * r + 544];
            v2f c2 = lds[swbase + 272 * r + 1088];
            v2f c3 = lds[swbase + 272 * r + 1632];
            v2f t0 = c0 + c2, t1 = c0 - c2;
            v2f t2 = c1 + c3, t3 = c1 - c3;
            v2f j3 = jrot<false>(t3);
            v2f y0 = t0 + t2;
            v2f y1 = t1 - j3;
            p += gelu2(y0 + Dh * us[r]);
            p += gelu2(y1 + Dh * us[r + 2]);
        }
    }
#pragma unroll
    for (int off = 32; off > 0; off >>= 1) {
        p.x += __shfl_down(p.x, off);
        p.y += __shfl_down(p.y, off);
    }
    if ((tid & 63) == 0) wred[tid >> 6] = p;
    __syncthreads();
    if (tid == 0) {
        v2f t = wred[0] + wred[1] + wred[2] + wred[3];
        float scale = fc_w[h] * (1.0f / (float)kL);
        partials[(size_t)pair * kH + h] = t * scale;
    }
}

// ---------------------------------------------------------------------------
// Final reduction: out[2p], out[2p+1] = sum_h partials[p][h] + bias.
// grid: 16 (one per pair), 256 threads.
// ---------------------------------------------------------------------------
__global__ __launch_bounds__(256) void reduce_kernel(const v2f* __restrict__ partials,
                                                     const float* __restrict__ fc_b,
                                                     float* __restrict__ out)
{
    __shared__ v2f wred[4];
    int pair = blockIdx.x, tid = threadIdx.x;
    v2f p = partials[(size_t)pair * kH + tid] + partials[(size_t)pair * kH + tid + 256];
#pragma unroll
    for (int off = 32; off > 0; off >>= 1) {
        p.x += __shfl_down(p.x, off);
        p.y += __shfl_down(p.y, off);
    }
    if ((tid & 63) == 0) wred[tid >> 6] = p;
    __syncthreads();
    if (tid == 0) {
        v2f t = wred[0] + wred[1] + wred[2] + wred[3];
        float bias = fc_b[0];
        out[2 * pair]     = t.x + bias;
        out[2 * pair + 1] = t.y + bias;
    }
}

// ---------------------------------------------------------------------------
extern "C" void kernel_launch(void* const* d_in, const int* in_sizes, int n_in,
                              void* d_out, int out_size, void* d_ws, size_t ws_size,
                              hipStream_t stream)
{
    const int*   x         = (const int*)d_in[0];
    const float* embedding = (const float*)d_in[1];
    const float* log_dt    = (const float*)d_in[2];
    const float* A_log     = (const float*)d_in[3];
    const float* A_imag    = (const float*)d_in[4];
    const float* C_re      = (const float*)d_in[5];
    const float* C_im      = (const float*)d_in[6];
    const float* Dv        = (const float*)d_in[7];
    const float* fc_w      = (const float*)d_in[8];
    const float* fc_b      = (const float*)d_in[9];
    float* out = (float*)d_out;

    char* ws = (char*)d_ws;
    const size_t act_bytes  = (size_t)kB * kH * kL * sizeof(float);       // 64 MiB
    const size_t khat_bytes = (size_t)kH * kNFFT * sizeof(float) * 2;     // 8 MiB / layer
    float* act  = (float*)ws;
    v2f*   Khat = (v2f*)(ws + act_bytes);

    const bool multi = ws_size >= act_bytes + kNL * khat_bytes;           // 96 MiB

    if (multi) {
        // partials (64 KiB) alias Khat layer-0's region: dead once conv(l0)
        // completes; conv_final reads only layer 3's slot.
        v2f* partials = Khat;
        prep_kernel<<<dim3(6144), 256, 0, stream>>>(x, embedding, act,
                                                    log_dt, A_log, A_imag,
                                                    C_re, C_im, Khat);
        for (int layer = 0; layer < kNL - 1; ++layer) {
            conv_kernel<<<dim3(kH, kB / 2), 256, 0, stream>>>(
                act, Khat + (size_t)layer * kH * kNFFT, Dv + layer * kH);
        }
        conv_final<<<dim3(kH, kB / 2), 256, 0, stream>>>(
            act, Khat + (size_t)(kNL - 1) * kH * kNFFT,
            Dv + (kNL - 1) * kH, fc_w, partials);
        reduce_kernel<<<dim3(kB / 2), 256, 0, stream>>>(partials, fc_b, out);
    } else {
        // fallback: single Khat slot; partials in their own region after it
        v2f* partials = (v2f*)(ws + act_bytes + khat_bytes);
        embed_kernel<<<dim3(4096), 256, 0, stream>>>(x, embedding, act);
        for (int layer = 0; layer < kNL - 1; ++layer) {
            kcomp_kernel<<<dim3(kH, 1), 256, 0, stream>>>(log_dt, A_log, A_imag,
                                                          C_re, C_im, Khat, layer, 0);
            conv_kernel<<<dim3(kH, kB / 2), 256, 0, stream>>>(act, Khat, Dv + layer * kH);
        }
        kcomp_kernel<<<dim3(kH, 1), 256, 0, stream>>>(log_dt, A_log, A_imag,
                                                      C_re, C_im, Khat, kNL - 1, 0);
        conv_final<<<dim3(kH, kB / 2), 256, 0, stream>>>(act, Khat,
                                                         Dv + (kNL - 1) * kH, fc_w, partials);
        reduce_kernel<<<dim3(kB / 2), 256, 0, stream>>>(partials, fc_b, out);
    }
}